// Round 5
// baseline (166.721 us; speedup 1.0000x reference)
//
#include <hip/hip_runtime.h>

// EquivariantGating: live math:
//   out0[z,w] = pw0*( sum_{u,v} s[z,u]s[z,v] W1[u,v,w] + INV_SQRT3*|v_z|^2*W4[w] )
//   out = (out0 @ WL)/16, split into two 512-vectors.
// GEMM M=512(z) N=256(w) K=65536(u,v); A[z,k]=s_u*s_v built on the fly (f16
// pk_mul), W1 staged f16. Block = 32u x 32v x 64w x 256z (z-split 2).
// 2-step rounds, register prefetch across a manual lgkm-only barrier.

typedef __attribute__((ext_vector_type(8))) _Float16 f16x8;
typedef __attribute__((ext_vector_type(2))) _Float16 f16x2;
typedef __attribute__((ext_vector_type(4))) float f32x4;
typedef __attribute__((ext_vector_type(2))) int int2v;
typedef __attribute__((ext_vector_type(4))) int int4v;

#define LDS_S 32768            // 256 z-rows * 128B (64 f16 cols, 16B slots swizzled)
#define BP 80                  // B tile: bytes per w-row (64B data + 16B pad)
#define BSTEP 5120             // 64 w * BP  (one u-step)
#define LDS_TOTAL (LDS_S + 4 * BSTEP)   // 2 bufs x 2 steps = 53248 B

// f32 pair -> packed f16 bits (v_cvt_pkrtz_f16_f32); builtin returns a
// __fp16 ext-vector on this toolchain, so go straight to bits via bit_cast.
__device__ __forceinline__ unsigned pkrtz(float a, float b) {
  return __builtin_bit_cast(unsigned, __builtin_amdgcn_cvt_pkrtz(a, b));
}
__device__ __forceinline__ int hbits(f16x2 h) {
  return __builtin_bit_cast(int, h);
}
__device__ __forceinline__ void barrier_lds() {
  // LDS-only drain: keep global prefetch loads in flight across the barrier
  asm volatile("s_waitcnt lgkmcnt(0)" ::: "memory");
  __builtin_amdgcn_s_barrier();
}

__global__ __launch_bounds__(256, 3) void eg_gemm(const float* __restrict__ s,
                                                  const float* __restrict__ W1,
                                                  float* __restrict__ out0) {
  extern __shared__ char smem[];
  char* sB = smem + LDS_S;

  const int bx = blockIdx.x;           // 512 = 2 zh * 8 uc * 8 vc * 4 wt
  const int zh = bx >> 8;
  const int uvw = bx & 255;
  const int wt = uvw & 3, vc = (uvw >> 2) & 7, uc = uvw >> 5;
  const int u0 = uc * 32, v0 = vc * 32, w0 = wt * 64;

  const int t = threadIdx.x;           // 256 = 4 waves
  const int lane = t & 63;
  const int wid = t >> 6;
  const int l15 = lane & 15;
  const int g = lane >> 4;

  // ---- stage s tile (f16): 256 z x 64 cols (u-chunk cols 0..31, v-chunk 32..63)
  // row = 128B = 8 slots of 16B; slot swizzled by (z&7)
  for (int j = 0; j < 16; ++j) {
    int id = j * 256 + t;              // 0..4095
    int zl = id >> 4;
    int c4 = id & 15;
    int srccol = (c4 < 8) ? (u0 + (c4 << 2)) : (v0 + ((c4 - 8) << 2));
    const float4 f = *(const float4*)(s + (zh * 256 + zl) * 256 + srccol);
    int slot = c4 >> 1;
    char* dst = smem + zl * 128 + (((slot ^ (zl & 7)) << 4) | ((c4 & 1) << 3));
    *(int2v*)dst = int2v{(int)pkrtz(f.x, f.y), (int)pkrtz(f.z, f.w)};
  }

  // ---- B staging setup: thread owns (w = t&63, v-quads vg and vg+4)
  const int wB = t & 63;
  const int vg = t >> 6;               // 0..3
  const int hsw = (wB >> 3) & 7;
  const int sl0 = (vg ^ hsw) << 3;
  const int sl1 = ((vg + 4) ^ hsw) << 3;
  const float* gB = W1 + (size_t)u0 * 65536 + (v0 + vg * 4) * 256 + w0 + wB;

  float pa0, pa1, pa2, pa3, pa4, pa5, pa6, pa7;   // prefetch: round's step p=0
  float pb0, pb1, pb2, pb3, pb4, pb5, pb6, pb7;   // step p=1

#define ISSUE(usbase)                                                       \
  do {                                                                      \
    const float* q0_ = gB + (size_t)(usbase) * 65536;                       \
    pa0 = q0_[0];    pa1 = q0_[256];      pa2 = q0_[512];  pa3 = q0_[768];  \
    pa4 = q0_[4096]; pa5 = q0_[4096+256]; pa6 = q0_[4096+512];              \
    pa7 = q0_[4096+768];                                                    \
    const float* q1_ = q0_ + 65536;                                         \
    pb0 = q1_[0];    pb1 = q1_[256];      pb2 = q1_[512];  pb3 = q1_[768];  \
    pb4 = q1_[4096]; pb5 = q1_[4096+256]; pb6 = q1_[4096+512];              \
    pb7 = q1_[4096+768];                                                    \
  } while (0)

#define WRITEPF(dst0_)                                                       \
  do {                                                                       \
    char* d0_ = (dst0_);                                                     \
    *(int2v*)(d0_ + wB * BP + sl0) =                                         \
        int2v{(int)pkrtz(pa0, pa1), (int)pkrtz(pa2, pa3)};                   \
    *(int2v*)(d0_ + wB * BP + sl1) =                                         \
        int2v{(int)pkrtz(pa4, pa5), (int)pkrtz(pa6, pa7)};                   \
    char* d1_ = d0_ + BSTEP;                                                 \
    *(int2v*)(d1_ + wB * BP + sl0) =                                         \
        int2v{(int)pkrtz(pb0, pb1), (int)pkrtz(pb2, pb3)};                   \
    *(int2v*)(d1_ + wB * BP + sl1) =                                         \
        int2v{(int)pkrtz(pb4, pb5), (int)pkrtz(pb6, pb7)};                   \
  } while (0)

  // ---- prologue: stage round 0 (us=0,1) directly into buf0; prefetch round 1
  ISSUE(0);
  WRITEPF(sB);
  ISSUE(2);
  barrier_lds();

  // ---- hoist sv fragments (v-chunk is K-loop invariant): 8 f16 per mf
  const int swz = l15 & 7;
  int4v sv[4];
#pragma unroll
  for (int mf = 0; mf < 4; ++mf) {
    const char* p = smem + (wid * 64 + mf * 16 + l15) * 128 + (((4 + g) ^ swz) << 4);
    sv[mf] = *(const int4v*)p;
  }

  // B-frag read addresses (per nf): slot-XORed
  int baddr[4];
#pragma unroll
  for (int nf = 0; nf < 4; ++nf) {
    int w = nf * 16 + l15;
    baddr[nf] = w * BP + (((2 * g) ^ ((w >> 3) & 7)) << 3);
  }

  f32x4 acc[4][4];
#pragma unroll
  for (int a = 0; a < 4; ++a)
#pragma unroll
    for (int b = 0; b < 4; ++b) acc[a][b] = 0.f;

  // ---- main loop: 8 groups (q) x 2 rounds (rr) x 2 steps (p); us = 4q+2rr+p
  for (int q = 0; q < 8; ++q) {
    // su for us in [4q,4q+4): b64 per mf (u-cols, 16B slot = 8 cols)
    int2v sur[4];
#pragma unroll
    for (int mf = 0; mf < 4; ++mf) {
      const char* p = smem + (wid * 64 + mf * 16 + l15) * 128 +
                      ((((q >> 1) ^ swz) << 4) | ((q & 1) << 3));
      sur[mf] = *(const int2v*)p;
    }
#pragma unroll
    for (int rr = 0; rr < 2; ++rr) {
      const int r = 2 * q + rr;                 // round 0..15
      const char* bufc = sB + rr * (2 * BSTEP); // compute buffer
      char* bufn = sB + (rr ^ 1) * (2 * BSTEP); // next buffer
#pragma unroll
      for (int p = 0; p < 2; ++p) {
        // A fragments: af[k] = f16(su * sv[k]) via v_pk_mul_f16
        f16x8 afr[4];
#pragma unroll
        for (int mf = 0; mf < 4; ++mf) {
          unsigned dw = (unsigned)sur[mf][rr];
          unsigned s2 = __builtin_amdgcn_perm(dw, dw, p ? 0x03020302u : 0x01000100u);
          f16x2 su2 = __builtin_bit_cast(f16x2, s2);
          int4v af;
#pragma unroll
          for (int jj = 0; jj < 4; ++jj) {
            f16x2 pv = __builtin_bit_cast(f16x2, (unsigned)sv[mf][jj]);
            f16x2 pr = su2 * pv;
            af[jj] = hbits(pr);
          }
          afr[mf] = __builtin_bit_cast(f16x8, af);
        }
        const char* bp = bufc + p * BSTEP;
#pragma unroll
        for (int nf = 0; nf < 4; ++nf) {
          int2v d0 = *(const int2v*)(bp + baddr[nf]);
          int2v d1 = *(const int2v*)(bp + (baddr[nf] ^ 8));
          int4v bf4 = int4v{d0[0], d0[1], d1[0], d1[1]};
          f16x8 bfr = __builtin_bit_cast(f16x8, bf4);
#pragma unroll
          for (int mf = 0; mf < 4; ++mf)
            acc[mf][nf] =
                __builtin_amdgcn_mfma_f32_16x16x32_f16(afr[mf], bfr, acc[mf][nf], 0, 0, 0);
        }
      }
      if (r < 15) WRITEPF(bufn);      // pf holds round r+1; write for next round
      if (r < 14) ISSUE(2 * (r + 2)); // prefetch round r+2 (stays in flight)
      if (r < 15) barrier_lds();
    }
  }

  // ---- epilogue: atomic accumulate (C/D: col=lane&15, row=4*(lane>>4)+r)
#pragma unroll
  for (int mf = 0; mf < 4; ++mf)
#pragma unroll
    for (int nf = 0; nf < 4; ++nf)
#pragma unroll
      for (int rI = 0; rI < 4; ++rI) {
        int z = zh * 256 + wid * 64 + mf * 16 + g * 4 + rI;
        int w = w0 + nf * 16 + l15;
        atomicAdd(out0 + z * 256 + w, acc[mf][nf][rI]);
      }
}

// Per z: add W4 term, scale by pw0, apply WL/16. One block (64 lanes) per z.
__global__ void eg_finish(const float* __restrict__ vec,
                          const float* __restrict__ W4,
                          const float* __restrict__ WL,
                          const float* __restrict__ acc,
                          float* __restrict__ out) {
  const int z = blockIdx.x;
  const int lane = threadIdx.x;
  float v0 = vec[z * 3 + 0], v1 = vec[z * 3 + 1], v2 = vec[z * 3 + 2];
  const float b = 0.57735026918962576f * (v0 * v0 + v1 * v1 + v2 * v2);
  float a0 = 0.f, a1 = 0.f;
#pragma unroll
  for (int j = 0; j < 4; ++j) {
    int w = j * 64 + lane;
    float o = acc[z * 256 + w] + b * W4[w];
    a0 += o * WL[2 * w];
    a1 += o * WL[2 * w + 1];
  }
#pragma unroll
  for (int off = 32; off > 0; off >>= 1) {
    a0 += __shfl_xor(a0, off);
    a1 += __shfl_xor(a1, off);
  }
  if (lane == 0) {
    // SCALE = pw0/16 = 1/(16*sqrt(65537))
    out[z] = 2.4413876e-04f * a0;
    out[512 + z] = 2.4413876e-04f * a1;
  }
}

extern "C" void kernel_launch(void* const* d_in, const int* in_sizes, int n_in,
                              void* d_out, int out_size, void* d_ws, size_t ws_size,
                              hipStream_t stream) {
  const float* vectors = (const float*)d_in[0];
  const float* scalars = (const float*)d_in[1];
  const float* W1 = (const float*)d_in[2];
  const float* W4 = (const float*)d_in[7];
  const float* WL = (const float*)d_in[8];
  float* out = (float*)d_out;
  float* acc = (float*)d_ws;  // 512*256 fp32 accumulator (512 KB)

  (void)hipMemsetAsync(acc, 0, 512 * 256 * sizeof(float), stream);
  eg_gemm<<<512, 256, LDS_TOTAL, stream>>>(scalars, W1, acc);
  eg_finish<<<512, 64, 0, stream>>>(vectors, W4, WL, acc, out);
}